// Round 12
// baseline (220.115 us; speedup 1.0000x reference)
//
#include <hip/hip_runtime.h>

// GriddingSample: trilinear sample of B dense 128^3 fp32 grids at B*N points.
// grid:   [B, 128^3] fp32   (d_in[0])
// pt:     [B, N, 3]  fp32   (d_in[1])  coords in [-64, 63) grid space
// scale:  [1] int            (d_in[2])  == 64 (fixed by problem geometry)
// out:    [B, N] fp32
//
// MEASUREMENT ROUND (instrumentation, deliberate): kernel launched TWICE.
// r8 (8 scalar gathers) = 195.45us, r11 (4x dwordx2) = 195.30us -> fusion
// neutral, noise +-0.2us, kernel's own duration invisible (<78us, below the
// harness's 512MiB 0xAA ws-fills in top-5). Score delta vs r11's 195.30
// == warm kernel duration, to sub-us precision. Decides: binning rewrite
// (if ~60-70us) vs roofline (if ~10-20us, matching line-traffic model).
// Second launch writes identical values (pure function of inputs) -> safe.

constexpr int GD  = 128;            // 2*SCALE voxels per side
constexpr int GD3 = GD * GD * GD;   // 2,097,152 voxels per batch
constexpr float SCALEF = 64.0f;

typedef float f2a4 __attribute__((ext_vector_type(2), aligned(4)));

template <bool SWZ>
__global__ __launch_bounds__(256) void gridding_sample_kernel(
    const float* __restrict__ grid,
    const float* __restrict__ pt,
    float* __restrict__ out,
    int npts,        // N points per batch
    int bpb_shift,   // log2(blocks per batch)            [SWZ path]
    int bpx_shift)   // log2(batches per XCD) = log2(B/8) [SWZ path]
{
    int b, nblk;
    if (SWZ) {
        // dispatch round-robins linear block id across 8 XCDs (heuristic):
        // give XCD x the contiguous batch range [x*B/8, (x+1)*B/8)
        const int id  = blockIdx.x;
        const int xcd = id & 7;
        const int s   = id >> 3;
        b    = (xcd << bpx_shift) + (s >> bpb_shift);
        nblk = s & ((1 << bpb_shift) - 1);
    } else {
        const int bpb = (npts + 255) >> 8;
        b    = blockIdx.x / bpb;
        nblk = blockIdx.x % bpb;
    }

    const int n = (nblk << 8) + threadIdx.x;
    if (n >= npts) return;

    const size_t idx = (size_t)b * npts + n;
    const float* __restrict__ g = grid + (size_t)b * GD3;

    // AoS [x,y,z]: wave reads 768 contiguous bytes -> coalesced.
    // Non-temporal: each coord is read once; don't pollute L2 with it.
    const float* pp = pt + idx * 3;
    float x = __builtin_nontemporal_load(pp + 0) + SCALEF;
    float y = __builtin_nontemporal_load(pp + 1) + SCALEF;
    float z = __builtin_nontemporal_load(pp + 2) + SCALEF;

    float xf = floorf(x), yf = floorf(y), zf = floorf(z);
    float fx = x - xf,    fy = y - yf,    fz = z - zf;

    // Clamp the BASE corner to [0, GD-2]: identical to the reference's
    // per-corner clip for all in-range coords (harness range [0,126.999)),
    // keeps +1 neighbors in-bounds for any input, and makes all neighbor
    // offsets compile-time constants.
    int ix = min(max((int)xf, 0), GD - 2);
    int iy = min(max((int)yf, 0), GD - 2);
    int iz = min(max((int)zf, 0), GD - 2);

    const float* p0 = g + ((ix << 14) + (iy << 7) + iz);   // x-plane 0
    const float* p1 = p0 + (GD * GD);                      // x-plane 1

    // 4 z-pair gathers (each = 8 contiguous bytes), issued back-to-back.
    f2a4 v00 = *(const f2a4*)(p0);        // g[iz], g[iz+1]           @ (x0,y0)
    f2a4 v01 = *(const f2a4*)(p0 + GD);   //                          @ (x0,y1)
    f2a4 v10 = *(const f2a4*)(p1);        //                          @ (x1,y0)
    f2a4 v11 = *(const f2a4*)(p1 + GD);   //                          @ (x1,y1)

    // trilinear lerp tree (7 fma) — fp32-equivalent to the 8-term weight sum
    float c00 = fmaf(fz, v00.y - v00.x, v00.x);
    float c01 = fmaf(fz, v01.y - v01.x, v01.x);
    float c10 = fmaf(fz, v10.y - v10.x, v10.x);
    float c11 = fmaf(fz, v11.y - v11.x, v11.x);
    float c0  = fmaf(fy, c01 - c00, c00);
    float c1  = fmaf(fy, c11 - c10, c10);
    __builtin_nontemporal_store(fmaf(fx, c1 - c0, c0), out + idx);
}

static inline bool is_pow2(int v) { return v > 0 && (v & (v - 1)) == 0; }
static inline int ilog2(int v) { int s = 0; while ((1 << s) < v) ++s; return s; }

extern "C" void kernel_launch(void* const* d_in, const int* in_sizes, int n_in,
                              void* d_out, int out_size, void* d_ws, size_t ws_size,
                              hipStream_t stream) {
    const float* grid = (const float*)d_in[0];
    const float* pt   = (const float*)d_in[1];
    float* out        = (float*)d_out;

    const int total = in_sizes[1] / 3;          // B*N
    const int B     = in_sizes[0] / GD3;        // 16
    const int npts  = total / B;                // N = 32768

    const int block = 256;
    const int bpb   = (npts + block - 1) / block;   // blocks per batch
    const int nblocks = bpb * B;

    if (npts % block == 0 && is_pow2(bpb) && B % 8 == 0 && is_pow2(B / 8)) {
        // TWO identical launches: score delta vs single-launch round 11
        // (195.30us) == warm kernel duration. Idempotent, capture-safe.
        gridding_sample_kernel<true><<<nblocks, block, 0, stream>>>(
            grid, pt, out, npts, ilog2(bpb), ilog2(B / 8));
        gridding_sample_kernel<true><<<nblocks, block, 0, stream>>>(
            grid, pt, out, npts, ilog2(bpb), ilog2(B / 8));
    } else {
        gridding_sample_kernel<false><<<nblocks, block, 0, stream>>>(
            grid, pt, out, npts, 0, 0);
        gridding_sample_kernel<false><<<nblocks, block, 0, stream>>>(
            grid, pt, out, npts, 0, 0);
    }
}

// Round 13
// 194.376 us; speedup vs baseline: 1.1324x; 1.1324x over previous
//
#include <hip/hip_runtime.h>

// GriddingSample: trilinear sample of B dense 128^3 fp32 grids at B*N points.
// grid:   [B, 128^3] fp32   (d_in[0])
// pt:     [B, N, 3]  fp32   (d_in[1])  coords in [-64, 63) grid space
// scale:  [1] int            (d_in[2])  == 64 (fixed by problem geometry)
// out:    [B, N] fp32
//
// FINAL FORM (revert of round-12's deliberate double-launch instrumentation).
// Measured ledger:
//   r8  (8 scalar gathers, single launch)  = 195.45 us
//   r11 (4x dwordx2 z-pair, single launch) = 195.30 us  -> fusion neutral,
//       kernel not VMEM-issue-bound; noise +-0.2 us
//   r12 (r11 kernel launched 2x)           = 220.12 us  -> warm kernel
//       duration = 24.8 us; rest of score (~170 us) is fixed harness
//       overhead (2x 78.5us 512MiB ws re-poison fills + d_in restore).
// Traffic model: ~4 distinct 64B lines/point x 524k points ~ 270 MB L2-fill
// served from L3 (16 MiB/XCD working set, XCD-swizzled) -> 18-27 us floor.
// Measured 24.8 us is inside the band => gather-line-traffic roofline.
// Binning/sort rewrite upper bound (+17 us) < its own cost => rejected.

constexpr int GD  = 128;            // 2*SCALE voxels per side
constexpr int GD3 = GD * GD * GD;   // 2,097,152 voxels per batch
constexpr float SCALEF = 64.0f;

typedef float f2a4 __attribute__((ext_vector_type(2), aligned(4)));

template <bool SWZ>
__global__ __launch_bounds__(256) void gridding_sample_kernel(
    const float* __restrict__ grid,
    const float* __restrict__ pt,
    float* __restrict__ out,
    int npts,        // N points per batch
    int bpb_shift,   // log2(blocks per batch)            [SWZ path]
    int bpx_shift)   // log2(batches per XCD) = log2(B/8) [SWZ path]
{
    int b, nblk;
    if (SWZ) {
        // dispatch round-robins linear block id across 8 XCDs (heuristic):
        // give XCD x the contiguous batch range [x*B/8, (x+1)*B/8)
        const int id  = blockIdx.x;
        const int xcd = id & 7;
        const int s   = id >> 3;
        b    = (xcd << bpx_shift) + (s >> bpb_shift);
        nblk = s & ((1 << bpb_shift) - 1);
    } else {
        const int bpb = (npts + 255) >> 8;
        b    = blockIdx.x / bpb;
        nblk = blockIdx.x % bpb;
    }

    const int n = (nblk << 8) + threadIdx.x;
    if (n >= npts) return;

    const size_t idx = (size_t)b * npts + n;
    const float* __restrict__ g = grid + (size_t)b * GD3;

    // AoS [x,y,z]: wave reads 768 contiguous bytes -> coalesced.
    // Non-temporal: each coord is read once; don't pollute L2 with it.
    const float* pp = pt + idx * 3;
    float x = __builtin_nontemporal_load(pp + 0) + SCALEF;
    float y = __builtin_nontemporal_load(pp + 1) + SCALEF;
    float z = __builtin_nontemporal_load(pp + 2) + SCALEF;

    float xf = floorf(x), yf = floorf(y), zf = floorf(z);
    float fx = x - xf,    fy = y - yf,    fz = z - zf;

    // Clamp the BASE corner to [0, GD-2]: identical to the reference's
    // per-corner clip for all in-range coords (harness range [0,126.999)),
    // keeps +1 neighbors in-bounds for any input, and makes all neighbor
    // offsets compile-time constants.
    int ix = min(max((int)xf, 0), GD - 2);
    int iy = min(max((int)yf, 0), GD - 2);
    int iz = min(max((int)zf, 0), GD - 2);

    const float* p0 = g + ((ix << 14) + (iy << 7) + iz);   // x-plane 0
    const float* p1 = p0 + (GD * GD);                      // x-plane 1

    // 4 z-pair gathers (each = 8 contiguous bytes), issued back-to-back.
    f2a4 v00 = *(const f2a4*)(p0);        // g[iz], g[iz+1]           @ (x0,y0)
    f2a4 v01 = *(const f2a4*)(p0 + GD);   //                          @ (x0,y1)
    f2a4 v10 = *(const f2a4*)(p1);        //                          @ (x1,y0)
    f2a4 v11 = *(const f2a4*)(p1 + GD);   //                          @ (x1,y1)

    // trilinear lerp tree (7 fma) — fp32-equivalent to the 8-term weight sum
    float c00 = fmaf(fz, v00.y - v00.x, v00.x);
    float c01 = fmaf(fz, v01.y - v01.x, v01.x);
    float c10 = fmaf(fz, v10.y - v10.x, v10.x);
    float c11 = fmaf(fz, v11.y - v11.x, v11.x);
    float c0  = fmaf(fy, c01 - c00, c00);
    float c1  = fmaf(fy, c11 - c10, c10);
    __builtin_nontemporal_store(fmaf(fx, c1 - c0, c0), out + idx);
}

static inline bool is_pow2(int v) { return v > 0 && (v & (v - 1)) == 0; }
static inline int ilog2(int v) { int s = 0; while ((1 << s) < v) ++s; return s; }

extern "C" void kernel_launch(void* const* d_in, const int* in_sizes, int n_in,
                              void* d_out, int out_size, void* d_ws, size_t ws_size,
                              hipStream_t stream) {
    const float* grid = (const float*)d_in[0];
    const float* pt   = (const float*)d_in[1];
    float* out        = (float*)d_out;

    const int total = in_sizes[1] / 3;          // B*N
    const int B     = in_sizes[0] / GD3;        // 16
    const int npts  = total / B;                // N = 32768

    const int block = 256;
    const int bpb   = (npts + block - 1) / block;   // blocks per batch
    const int nblocks = bpb * B;

    if (npts % block == 0 && is_pow2(bpb) && B % 8 == 0 && is_pow2(B / 8)) {
        gridding_sample_kernel<true><<<nblocks, block, 0, stream>>>(
            grid, pt, out, npts, ilog2(bpb), ilog2(B / 8));
    } else {
        gridding_sample_kernel<false><<<nblocks, block, 0, stream>>>(
            grid, pt, out, npts, 0, 0);
    }
}